// Round 4
// baseline (338.392 us; speedup 1.0000x reference)
//
#include <hip/hip_runtime.h>

// Problem: preds (N=8,S=6,C=4,H=512,W=512) fp32, targets (8,6,512,512) int.
// out = (1/N) * sum [logsumexp_c(preds) - preds[target]]   (scalar)
//
// R1: 12288 same-address atomicAdds serialized (168 us flat).
// R2: two-stage reduction -> 310 us; top-5 all harness d_ws-poison fills.
// R3: MLP boost (10 loads in flight) -> neutral => ce_partial is BW-floor.
// R4: fuse final reduction via last-block-done (agent-scope atomics);
//     removes ce_final dispatch + graph dependency gap.

#define HW        (512 * 512)
#define QUADS     (HW / 4)          // 65536 float4 groups per channel plane
#define NS        48                // N*S
#define TOTALQ    (NS * QUADS)      // 3145728 quads
#define NBLK      1024
#define ITERS     (TOTALQ / (NBLK * 256))   // 12, exact
#define INV_N     0.125f

__device__ __forceinline__ float nll_one(float a, float b, float c, float d, int t) {
    float m = fmaxf(fmaxf(a, b), fmaxf(c, d));
    float s = __expf(a - m) + __expf(b - m) + __expf(c - m) + __expf(d - m);
    float lse = m + __logf(s);
    float xt = (t == 0) ? a : ((t == 1) ? b : ((t == 2) ? c : d));
    return lse - xt;
}

__device__ __forceinline__ float nll_quad(float4 x0, float4 x1, float4 x2, float4 x3, int4 t) {
    return nll_one(x0.x, x1.x, x2.x, x3.x, t.x)
         + nll_one(x0.y, x1.y, x2.y, x3.y, t.y)
         + nll_one(x0.z, x1.z, x2.z, x3.z, t.z)
         + nll_one(x0.w, x1.w, x2.w, x3.w, t.w);
}

__global__ __launch_bounds__(256) void ce_fused(const float* __restrict__ preds,
                                                const int* __restrict__ targets,
                                                int* __restrict__ counter,   // d_ws[0], pre-zeroed
                                                float* __restrict__ part,    // d_ws+256, NBLK floats
                                                float* __restrict__ out) {
    const float4* __restrict__ p4 = (const float4*)preds;
    const int4*   __restrict__ t4 = (const int4*)targets;

    float lsum = 0.0f;
    const int g0 = blockIdx.x * (ITERS * 256) + threadIdx.x;

    #pragma unroll
    for (int it = 0; it < ITERS; it += 2) {
        const int ga  = g0 + it * 256;
        const int gb  = ga + 256;
        const int nsa = ga >> 16, qa = ga & (QUADS - 1);
        const int nsb = gb >> 16, qb = gb & (QUADS - 1);
        const int ba  = (nsa << 2) * QUADS + qa;
        const int bb  = (nsb << 2) * QUADS + qb;

        float4 a0 = p4[ba];
        float4 a1 = p4[ba + QUADS];
        float4 a2 = p4[ba + 2 * QUADS];
        float4 a3 = p4[ba + 3 * QUADS];
        float4 b0 = p4[bb];
        float4 b1 = p4[bb + QUADS];
        float4 b2 = p4[bb + 2 * QUADS];
        float4 b3 = p4[bb + 3 * QUADS];
        int4   ta = t4[nsa * QUADS + qa];
        int4   tb = t4[nsb * QUADS + qb];

        lsum += nll_quad(a0, a1, a2, a3, ta);
        lsum += nll_quad(b0, b1, b2, b3, tb);
    }

    // wave-64 reduction
    #pragma unroll
    for (int off = 32; off > 0; off >>= 1)
        lsum += __shfl_down(lsum, off, 64);

    __shared__ float wsum[4];
    __shared__ int   is_last;
    const int lane = threadIdx.x & 63;
    const int wave = threadIdx.x >> 6;
    if (lane == 0) wsum[wave] = lsum;
    __syncthreads();

    if (threadIdx.x == 0) {
        float bsum = (wsum[0] + wsum[1] + wsum[2] + wsum[3]) * INV_N;
        // device-scope publish of this block's partial, then count in
        __hip_atomic_store(&part[blockIdx.x], bsum, __ATOMIC_RELAXED,
                           __HIP_MEMORY_SCOPE_AGENT);
        int old = __hip_atomic_fetch_add(counter, 1, __ATOMIC_ACQ_REL,
                                         __HIP_MEMORY_SCOPE_AGENT);
        is_last = (old == NBLK - 1);
    }
    __syncthreads();

    if (is_last) {
        float s = 0.0f;
        #pragma unroll
        for (int i = 0; i < NBLK / 256; ++i)
            s += __hip_atomic_load(&part[i * 256 + threadIdx.x], __ATOMIC_RELAXED,
                                   __HIP_MEMORY_SCOPE_AGENT);
        #pragma unroll
        for (int off = 32; off > 0; off >>= 1)
            s += __shfl_down(s, off, 64);
        if (lane == 0) wsum[wave] = s;
        __syncthreads();
        if (threadIdx.x == 0)
            out[0] = wsum[0] + wsum[1] + wsum[2] + wsum[3];
    }
}

extern "C" void kernel_launch(void* const* d_in, const int* in_sizes, int n_in,
                              void* d_out, int out_size, void* d_ws, size_t ws_size,
                              hipStream_t stream) {
    const float* preds   = (const float*)d_in[0];
    const int*   targets = (const int*)d_in[1];
    int*         counter = (int*)d_ws;                       // 4 B, zeroed below
    float*       part    = (float*)((char*)d_ws + 256);      // NBLK floats
    float*       out     = (float*)d_out;

    hipMemsetAsync(counter, 0, sizeof(int), stream);
    ce_fused<<<NBLK, 256, 0, stream>>>(preds, targets, counter, part, out);
}

// Round 5
// 298.320 us; speedup vs baseline: 1.1343x; 1.1343x over previous
//
#include <hip/hip_runtime.h>

// Problem: preds (N=8,S=6,C=4,H=512,W=512) fp32, targets (8,6,512,512) int.
// out = (1/N) * sum [logsumexp_c(preds) - preds[target]]   (scalar)
//
// R1: 12288 same-address atomicAdds serialized (168 us flat).
// R2: two-stage reduction -> 310 us; harness d_ws-poison dominates top-5.
// R3: MLP unroll-2 -> neutral.
// R4: fused last-block-done -> VGPR 124, occupancy 18%, latency-bound 129 us
//     (L3-warm replay same time => latency, not BW). REGRESSION.
// R5: max-concurrency: R1's 16-VGPR 1-quad/thread body (12288 blocks,
//     occ ~65%) + plain per-block partial store; tiny second kernel.

#define HW        (512 * 512)
#define QUADS     (HW / 4)          // 65536 float4 groups per channel plane
#define NS        48                // N*S
#define NBLK      ((NS * QUADS) / 256)   // 12288 blocks, 1 quad per thread
#define INV_N     0.125f

__device__ __forceinline__ float nll_one(float a, float b, float c, float d, int t) {
    float m = fmaxf(fmaxf(a, b), fmaxf(c, d));
    float s = __expf(a - m) + __expf(b - m) + __expf(c - m) + __expf(d - m);
    float lse = m + __logf(s);
    float xt = (t == 0) ? a : ((t == 1) ? b : ((t == 2) ? c : d));
    return lse - xt;
}

__global__ __launch_bounds__(256) void ce_partial(const float* __restrict__ preds,
                                                  const int* __restrict__ targets,
                                                  float* __restrict__ part) {
    const int g  = blockIdx.x * 256 + threadIdx.x;  // global quad index
    const int ns = g >> 16;                          // g / QUADS
    const int q  = g & (QUADS - 1);                  // g % QUADS

    const float4* __restrict__ p4 = (const float4*)preds;
    const int4*   __restrict__ t4 = (const int4*)targets;

    const int base = (ns << 2) * QUADS + q;
    float4 x0 = p4[base];
    float4 x1 = p4[base + QUADS];
    float4 x2 = p4[base + 2 * QUADS];
    float4 x3 = p4[base + 3 * QUADS];
    int4   t  = t4[ns * QUADS + q];

    float lsum = nll_one(x0.x, x1.x, x2.x, x3.x, t.x)
               + nll_one(x0.y, x1.y, x2.y, x3.y, t.y)
               + nll_one(x0.z, x1.z, x2.z, x3.z, t.z)
               + nll_one(x0.w, x1.w, x2.w, x3.w, t.w);

    // wave-64 reduction
    #pragma unroll
    for (int off = 32; off > 0; off >>= 1)
        lsum += __shfl_down(lsum, off, 64);

    __shared__ float wsum[4];
    const int lane = threadIdx.x & 63;
    const int wave = threadIdx.x >> 6;
    if (lane == 0) wsum[wave] = lsum;
    __syncthreads();
    if (threadIdx.x == 0)
        part[blockIdx.x] = (wsum[0] + wsum[1] + wsum[2] + wsum[3]) * INV_N;
}

__global__ __launch_bounds__(256) void ce_final(const float* __restrict__ part,
                                                float* __restrict__ out) {
    float lsum = 0.0f;
    #pragma unroll
    for (int i = 0; i < NBLK / 256; ++i)          // 48 iterations
        lsum += part[i * 256 + threadIdx.x];

    #pragma unroll
    for (int off = 32; off > 0; off >>= 1)
        lsum += __shfl_down(lsum, off, 64);

    __shared__ float wsum[4];
    const int lane = threadIdx.x & 63;
    const int wave = threadIdx.x >> 6;
    if (lane == 0) wsum[wave] = lsum;
    __syncthreads();
    if (threadIdx.x == 0)
        out[0] = wsum[0] + wsum[1] + wsum[2] + wsum[3];
}

extern "C" void kernel_launch(void* const* d_in, const int* in_sizes, int n_in,
                              void* d_out, int out_size, void* d_ws, size_t ws_size,
                              hipStream_t stream) {
    const float* preds   = (const float*)d_in[0];
    const int*   targets = (const int*)d_in[1];
    float*       part    = (float*)d_ws;     // NBLK floats = 48 KiB scratch
    float*       out     = (float*)d_out;

    ce_partial<<<NBLK, 256, 0, stream>>>(preds, targets, part);
    ce_final<<<1, 256, 0, stream>>>(part, out);
}